// Round 7
// baseline (44.228 us; speedup 1.0000x reference)
//
#include <hip/hip_runtime.h>

#define NB 8
#define NP 131072
#define NM 16
#define THRESH 0.5f
#define BLK 256
#define PPT 4                    // priors per thread
#define PPB (BLK * PPT)          // 1024 priors per block
#define BPB (NP / PPB)           // 128 blocks per batch
#define NPAIR (NB * NM)          // 128 (b,m) pairs
#define NBLOCKS (NB * BPB)       // 1024

typedef unsigned long long u64;
typedef unsigned int u32;

// ---------- DPP wave-64 reductions ----------
// row_shr 1,2,4,8 then row_bcast:15, row_bcast:31; lane 63 holds the result.
// old=0 fill is harmless for sum (adds 0) and max of non-negatives.

template <int CTRL>
__device__ __forceinline__ float dppmv(float x) {
    return __int_as_float(__builtin_amdgcn_update_dpp(
        0, __float_as_int(x), CTRL, 0xf, 0xf, false));
}

__device__ __forceinline__ float wave_max63(float x) {   // x >= 0 required
    x = fmaxf(x, dppmv<0x111>(x));
    x = fmaxf(x, dppmv<0x112>(x));
    x = fmaxf(x, dppmv<0x114>(x));
    x = fmaxf(x, dppmv<0x118>(x));
    x = fmaxf(x, dppmv<0x142>(x));
    x = fmaxf(x, dppmv<0x143>(x));
    return x;
}

__device__ __forceinline__ float wave_sum63(float x) {
    x += dppmv<0x111>(x);
    x += dppmv<0x112>(x);
    x += dppmv<0x114>(x);
    x += dppmv<0x118>(x);
    x += dppmv<0x142>(x);
    x += dppmv<0x143>(x);
    return x;
}

__device__ __forceinline__ float bcast63(float x) {
    return __int_as_float(__builtin_amdgcn_readlane(__float_as_int(x), 63));
}

// ---------- shared math (identical formulas everywhere) ----------

__device__ __forceinline__ float iou_term(float inter, float va, float vb) {
    return (inter > 0.0f) ? inter * __builtin_amdgcn_rcpf(va + vb - inter) : 0.0f;
}

__device__ __forceinline__ float iou_box(const float4 A, const float4 B4,
                                         const float pl[3], const float ph[3],
                                         float vb) {
    float d0 = fminf(A.w,  ph[0]) - fmaxf(A.x, pl[0]);
    float d1 = fminf(B4.x, ph[1]) - fmaxf(A.y, pl[1]);
    float d2 = fminf(B4.y, ph[2]) - fmaxf(A.z, pl[2]);
    float inter = fmaxf(d0, 0.0f) * fmaxf(d1, 0.0f) * fmaxf(d2, 0.0f);
    return iou_term(inter, B4.z, vb);
}

__device__ __forceinline__ float focal_term(float x, bool pos) {
    float t = __expf(-fabsf(x));                 // e^{-|x|}
    float r = __builtin_amdgcn_rcpf(1.0f + t);   // 1/(1+t)
    float L = __logf(1.0f + t);                  // log1p(e^{-|x|})
    float ce = (pos ? fmaxf(-x, 0.0f) : fmaxf(x, 0.0f)) + L;   // softplus
    float omp = (pos == (x >= 0.0f)) ? t * r : r;              // 1 - pt
    float w = pos ? 0.25f : 0.75f;
    return w * omp * omp * ce;
}

__device__ __forceinline__ float l1_enc(const float* lp,
                                        const float blo[3], const float bhi[3],
                                        const float pc[3], const float ps[3]) {
    float s = 0.0f;
#pragma unroll
    for (int k = 0; k < 3; ++k) {
        float gc = (blo[k] + bhi[k]) / 2.0f;
        float gs = bhi[k] - blo[k];
        float e  = (gc - pc[k]) / (ps[k] / 10.0f);
        float e2 = __logf(gs / ps[k]) * 5.0f;
        s += fabsf(lp[k]     - e);
        s += fabsf(lp[3 + k] - e2);
    }
    return s;
}

__device__ __forceinline__ u32 decode_p(u64 k) { return ~(u32)(k & 0xFFFFFFFFull); }

// ---------- fused kernel: match + partials + last-block finalize ----------

__global__ __launch_bounds__(BLK) void match_loss_kernel(
        const float* __restrict__ locs, const float* __restrict__ scores,
        const float* __restrict__ boxes, const int* __restrict__ labels,
        const float* __restrict__ priors,
        u64* __restrict__ keys,                  // [NPAIR], pre-zeroed, atomicMax
        u32* __restrict__ counter,               // pre-zeroed
        float4* __restrict__ part,               // [NBLOCKS]
        float* __restrict__ out) {
    __shared__ float4 s_box[NM][2];              // {lo0,lo1,lo2,hi0} {hi1,hi2,va,lab}
    __shared__ u64    s_wkey[4][NM];
    __shared__ float  s_wred[4][3];
    __shared__ u64    s_key[NPAIR];              // finalize only
    __shared__ float  s_red[4][3], s_fix[4][3];  // finalize only
    __shared__ u32    s_last;

    const int tid  = threadIdx.x;
    const int b    = blockIdx.y;
    const int lane = tid & 63, wave = tid >> 6;
    const int p0   = blockIdx.x * PPB + PPT * tid;   // multiple of 4

    if (tid < NM) {
        const float* bx = &boxes[(b * NM + tid) * 6];
        float l0 = bx[0], l1 = bx[1], l2 = bx[2];
        float h0 = bx[3], h1 = bx[4], h2 = bx[5];
        s_box[tid][0] = make_float4(l0, l1, l2, h0);
        float va = (h0 - l0) * (h1 - l1) * (h2 - l2);
        s_box[tid][1] = make_float4(h1, h2, va, __int_as_float(labels[b * NM + tid]));
    }
    __syncthreads();

    // 4 priors: 6 aligned float4 loads
    const float4* pr4 = reinterpret_cast<const float4*>(priors);
    const size_t f4b = (size_t)(p0 / 2) * 3;
    float4 q0 = pr4[f4b + 0], q1 = pr4[f4b + 1], q2 = pr4[f4b + 2];
    float4 q3 = pr4[f4b + 3], q4 = pr4[f4b + 4], q5 = pr4[f4b + 5];
    float pl[PPT][3], ph[PPT][3], vb[PPT];
    {
        const float qf[24] = {q0.x,q0.y,q0.z,q0.w, q1.x,q1.y,q1.z,q1.w,
                              q2.x,q2.y,q2.z,q2.w, q3.x,q3.y,q3.z,q3.w,
                              q4.x,q4.y,q4.z,q4.w, q5.x,q5.y,q5.z,q5.w};
#pragma unroll
        for (int j = 0; j < PPT; ++j) {
#pragma unroll
            for (int k = 0; k < 3; ++k) {
                float c = qf[6 * j + k], s = qf[6 * j + 3 + k];
                pl[j][k] = c - s / 2.0f;             // mirror reference op order
                ph[j][k] = c + s / 2.0f;
            }
            vb[j] = (ph[j][0] - pl[j][0]) * (ph[j][1] - pl[j][1]) * (ph[j][2] - pl[j][2]);
        }
    }

    // phase 1: per-m in-lane best over the 4 priors (ascending p, strict >)
    float ci[NM]; u32 cp[NM];
    float best[PPT]; int bm[PPT];
#pragma unroll
    for (int j = 0; j < PPT; ++j) { best[j] = -1.0f; bm[j] = 0; }
#pragma unroll
    for (int m = 0; m < NM; ++m) {
        float4 A = s_box[m][0], B4 = s_box[m][1];
        float i0 = iou_box(A, B4, pl[0], ph[0], vb[0]);
        float i1 = iou_box(A, B4, pl[1], ph[1], vb[1]);
        float i2 = iou_box(A, B4, pl[2], ph[2], vb[2]);
        float i3 = iou_box(A, B4, pl[3], ph[3], vb[3]);
        if (i0 > best[0]) { best[0] = i0; bm[0] = m; }   // strict > = first max
        if (i1 > best[1]) { best[1] = i1; bm[1] = m; }
        if (i2 > best[2]) { best[2] = i2; bm[2] = m; }
        if (i3 > best[3]) { best[3] = i3; bm[3] = m; }
        float v = i0; u32 w = (u32)p0;
        if (i1 > v) { v = i1; w = (u32)(p0 + 1); }
        if (i2 > v) { v = i2; w = (u32)(p0 + 2); }
        if (i3 > v) { v = i3; w = (u32)(p0 + 3); }
        ci[m] = v; cp[m] = w;
    }

    // phase 2: 16 independent wave-max chains (back-to-back for ILP)
#pragma unroll
    for (int m = 0; m < NM; ++m) {
        float wm = bcast63(wave_max63(ci[m]));
        u64 eq = __ballot(ci[m] == wm);
        int ls = __ffsll(eq) - 1;                    // lowest lane = lowest p
        u32 wp = (u32)__builtin_amdgcn_readlane((int)cp[m], ls);
        if (lane == 0)
            s_wkey[wave][m] = ((u64)__float_as_uint(wm) << 32) | (u32)~wp;
    }

    // pre-override losses for the 4 priors
    const float4* sc4 = reinterpret_cast<const float4*>(scores);
    const size_t scb = ((size_t)b * NP + p0) >> 1;
    float4 sA = sc4[scb], sB = sc4[scb + 1];
    const float xs[PPT] = {sA.y, sA.w, sB.y, sB.w};

    float f = 0.0f, l = 0.0f, n = 0.0f;
#pragma unroll
    for (int j = 0; j < PPT; ++j) {
        float4 Bb = s_box[bm[j]][1];
        const bool pos = (best[j] >= THRESH) && (__float_as_int(Bb.w) > 0);
        f += focal_term(xs[j], pos);
        if (pos) {                                   // rare: reload prior pc/ps
            const int p = p0 + j;
            float pc[3], ps[3];
#pragma unroll
            for (int k = 0; k < 3; ++k) { pc[k] = priors[p * 6 + k]; ps[k] = priors[p * 6 + 3 + k]; }
            float4 Ab = s_box[bm[j]][0];
            float blo[3] = {Ab.x, Ab.y, Ab.z}, bhi[3] = {Ab.w, Bb.x, Bb.y};
            l += l1_enc(&locs[((size_t)b * NP + p) * 6], blo, bhi, pc, ps);
            n += 1.0f;
        }
    }

    f = wave_sum63(f); l = wave_sum63(l); n = wave_sum63(n);
    if (lane == 63) { s_wred[wave][0] = f; s_wred[wave][1] = l; s_wred[wave][2] = n; }
    __syncthreads();

    if (tid < NM) {
        u64 k = s_wkey[0][tid];
#pragma unroll
        for (int w = 1; w < 4; ++w) k = (s_wkey[w][tid] > k) ? s_wkey[w][tid] : k;
        atomicMax(&keys[b * NM + tid], k);           // 16 atomics/block, 128 addrs
    }
    if (tid == 0) {
        part[b * BPB + blockIdx.x] =
            make_float4(s_wred[0][0] + s_wred[1][0] + s_wred[2][0] + s_wred[3][0],
                        s_wred[0][1] + s_wred[1][1] + s_wred[2][1] + s_wred[3][1],
                        s_wred[0][2] + s_wred[1][2] + s_wred[2][2] + s_wred[3][2],
                        0.0f);
    }
    __syncthreads();                                 // drains this block's vmem ops

    if (tid == 0) {                                  // release + arrive
        __threadfence();
        s_last = (atomicAdd(counter, 1u) == (u32)(NBLOCKS - 1)) ? 1u : 0u;
    }
    __syncthreads();
    if (!s_last) return;

    // ================= last block: finalize =================
    __threadfence();                                 // acquire

    // 1) reduce per-block loss partials (4 per thread, fixed order)
    float rf = 0.0f, rl = 0.0f, rn = 0.0f;
    for (int i = tid; i < NBLOCKS; i += BLK) {
        float4 v = part[i]; rf += v.x; rl += v.y; rn += v.z;
    }
    rf = wave_sum63(rf); rl = wave_sum63(rl); rn = wave_sum63(rn);
    if (lane == 63) { s_red[wave][0] = rf; s_red[wave][1] = rl; s_red[wave][2] = rn; }

    // 2) keys are already globally reduced by atomicMax
    if (tid < NPAIR) s_key[tid] = keys[tid];
    __syncthreads();

    // 3) per-(b,m) override fixup
    float df = 0.0f, dl = 0.0f, dn = 0.0f;
    if (tid < NPAIR) {
        const int bb = tid / NM, m = tid % NM;
        const u32 pstar = decode_p(s_key[tid]);
        bool skip = false;                        // duplicate prior: last m wins
        for (int mm = m + 1; mm < NM; ++mm)
            skip |= (decode_p(s_key[bb * NM + mm]) == pstar);
        if (!skip) {
            const int p = (int)pstar;
            float pc[3], ps[3], fl[3], fh[3];
#pragma unroll
            for (int k = 0; k < 3; ++k) { pc[k] = priors[p * 6 + k]; ps[k] = priors[p * 6 + 3 + k]; }
#pragma unroll
            for (int k = 0; k < 3; ++k) { fl[k] = pc[k] - ps[k] / 2.0f; fh[k] = pc[k] + ps[k] / 2.0f; }
            const float fvb = (fh[0] - fl[0]) * (fh[1] - fl[1]) * (fh[2] - fl[2]);

            // recompute this prior's original best match (bit-identical math)
            float fbest = -1.0f; int fbm = 0;
            for (int mm = 0; mm < NM; ++mm) {
                const float* bx = &boxes[(bb * NM + mm) * 6];
                float d0 = fminf(bx[3], fh[0]) - fmaxf(bx[0], fl[0]);
                float d1 = fminf(bx[4], fh[1]) - fmaxf(bx[1], fl[1]);
                float d2 = fminf(bx[5], fh[2]) - fmaxf(bx[2], fl[2]);
                float inter = fmaxf(d0, 0.0f) * fmaxf(d1, 0.0f) * fmaxf(d2, 0.0f);
                float va = (bx[3] - bx[0]) * (bx[4] - bx[1]) * (bx[5] - bx[2]);
                float iou = iou_term(inter, va, fvb);
                if (iou > fbest) { fbest = iou; fbm = mm; }
            }
            const bool old_pos = (fbest >= THRESH) && (labels[bb * NM + fbm] > 0);
            const bool new_pos = (labels[bb * NM + m] > 0);  // overlap forced to 1.0

            const float x = scores[((size_t)bb * NP + p) * 2 + 1];
            df = focal_term(x, new_pos) - focal_term(x, old_pos);
            dn = (new_pos ? 1.0f : 0.0f) - (old_pos ? 1.0f : 0.0f);

            const float* lp = &locs[((size_t)bb * NP + p) * 6];
            if (new_pos) {
                const float* bx = &boxes[(bb * NM + m) * 6];
                float blo[3] = {bx[0], bx[1], bx[2]}, bhi[3] = {bx[3], bx[4], bx[5]};
                dl += l1_enc(lp, blo, bhi, pc, ps);
            }
            if (old_pos) {
                const float* bx = &boxes[(bb * NM + fbm) * 6];
                float blo[3] = {bx[0], bx[1], bx[2]}, bhi[3] = {bx[3], bx[4], bx[5]};
                dl -= l1_enc(lp, blo, bhi, pc, ps);
            }
        }
    }
    df = wave_sum63(df); dl = wave_sum63(dl); dn = wave_sum63(dn);
    if (lane == 63) { s_fix[wave][0] = df; s_fix[wave][1] = dl; s_fix[wave][2] = dn; }
    __syncthreads();

    // 4) finalize (single thread, fixed order)
    if (tid == 0) {
        float tf = 0.0f, tl = 0.0f, tn = 0.0f;
        for (int w = 0; w < 4; ++w) {
            tf += s_red[w][0] + s_fix[w][0];
            tl += s_red[w][1] + s_fix[w][1];
            tn += s_red[w][2] + s_fix[w][2];
        }
        out[0] = tf / (float)(NB * NP);                                   // conf_loss
        out[1] = (tn > 0.5f) ? tl / fmaxf(tn * 6.0f, 1.0f) : 0.0f;        // loc_loss
    }
}

// ---------- launch: tiny memset + one fused kernel ----------

extern "C" void kernel_launch(void* const* d_in, const int* in_sizes, int n_in,
                              void* d_out, int out_size, void* d_ws, size_t ws_size,
                              hipStream_t stream) {
    const float* locs   = (const float*)d_in[0];
    const float* scores = (const float*)d_in[1];
    const float* boxes  = (const float*)d_in[2];
    const int*   labels = (const int*)d_in[3];
    const float* priors = (const float*)d_in[4];
    float* out = (float*)d_out;

    u64*    keys    = (u64*)d_ws;                            // 1024 B
    u32*    counter = (u32*)((char*)d_ws + 1024);            // 4 B
    float4* part    = (float4*)((char*)d_ws + 2048);         // 16 KB

    hipMemsetAsync(d_ws, 0, 2048, stream);                   // keys + counter

    dim3 grid(BPB, NB);
    match_loss_kernel<<<grid, BLK, 0, stream>>>(locs, scores, boxes, labels, priors,
                                                keys, counter, part, out);
}